// Round 10
// baseline (1484.953 us; speedup 1.0000x reference)
//
#include <hip/hip_runtime.h>
#include <hip/hip_cooperative_groups.h>

namespace cg = cooperative_groups;

#define N_NODES 20000
#define S_COLS  4096
#define E_EDGES 640000
#define D_DIM   256
#define NJOBS   5008         // 1252 row-tiles (16 rows) x 4 col-tiles (64 cols)

typedef unsigned short bf16_t;
typedef __attribute__((ext_vector_type(8))) short short8;
typedef __attribute__((ext_vector_type(4))) float f32x4;

__device__ __forceinline__ float bf2f(bf16_t u) {
    union { unsigned int i; float f; } v; v.i = ((unsigned int)u) << 16; return v.f;
}
__device__ __forceinline__ bf16_t f2bf(float x) {   // round-to-nearest-even
    union { float f; unsigned int i; } v; v.f = x;
    unsigned int r = v.i + 0x7FFF + ((v.i >> 16) & 1);
    return (bf16_t)(r >> 16);
}
__device__ __forceinline__ float lo_bf(unsigned int u) {
    union { unsigned int i; float f; } v; v.i = u << 16; return v.f;
}
__device__ __forceinline__ float hi_bf(unsigned int u) {
    union { unsigned int i; float f; } v; v.i = u & 0xFFFF0000u; return v.f;
}
__device__ __forceinline__ unsigned int pack_bf(float a, float b) {
    return (unsigned int)f2bf(a) | ((unsigned int)f2bf(b) << 16);
}

// ===========================================================================
// PATH A: single cooperative kernel (phases split by grid.sync()).
// Register-light phases only (bf16 t, acc[4] GEMM tiles).
// ===========================================================================
__global__ __launch_bounds__(256, 3)
void fused_kernel(const float* __restrict__ init_m, const int* __restrict__ eidx,
                  const float* __restrict__ attr,
                  const float* __restrict__ w1, const float* __restrict__ b1,
                  const float* __restrict__ w2, const float* __restrict__ b2,
                  const float* __restrict__ Wm, float* __restrict__ out,
                  bf16_t* __restrict__ hbuf, bf16_t* __restrict__ tbuf,
                  bf16_t* __restrict__ Wt_hi, bf16_t* __restrict__ Wt_lo,
                  int* __restrict__ cnt, int* __restrict__ offs,
                  int* __restrict__ cur, int* __restrict__ src_s,
                  float* __restrict__ attr_s) {
    cg::grid_group grid = cg::this_grid();
    __shared__ float w2s[16][256];
    __shared__ int   list[1024];
    __shared__ int   cnt_s;
    __shared__ float fred[4][16];
    __shared__ float ftot[16];
    __shared__ int   sdata[256];

    const int t     = threadIdx.x;
    const int b     = blockIdx.x;
    const int nblk  = gridDim.x;
    const int nthr  = nblk * 256;
    const int nwave = nthr >> 6;
    const int gtid  = b * 256 + t;
    const int wave  = t >> 6, lane = t & 63;
    const int gwave = gtid >> 6;
    const int quad  = lane >> 4, id16 = lane & 15;
    const int half  = lane >> 5, l32 = lane & 31;

    // ---- P1: zero cnt; W transpose + fp32->bf16 hi/lo split ----
    for (int i = gtid; i < N_NODES; i += nthr) cnt[i] = 0;
    for (int i = gtid; i < 65536; i += nthr) {
        int k = i >> 8, n = i & 255;
        float w = Wm[k * 256 + n];
        bf16_t hi = f2bf(w);
        bf16_t lo = f2bf(w - bf2f(hi));
        Wt_hi[n * 256 + k] = hi;
        Wt_lo[n * 256 + k] = lo;
    }
    grid.sync();

    // ---- P2: count edges per destination ----
    for (int e = gtid; e < E_EDGES; e += nthr)
        atomicAdd(&cnt[eidx[E_EDGES + e]], 1);
    grid.sync();

    // ---- P3: exclusive scan (block 0; 256 thr x 79 elems) ----
    if (b == 0) {
        int base = t * 79;
        int local = 0;
        for (int k = 0; k < 79; ++k) {
            int idx = base + k;
            if (idx < N_NODES) local += cnt[idx];
        }
        sdata[t] = local;
        __syncthreads();
        for (int off = 1; off < 256; off <<= 1) {
            int v = (t >= off) ? sdata[t - off] : 0;
            __syncthreads();
            sdata[t] += v;
            __syncthreads();
        }
        int prefix = (t == 0) ? 0 : sdata[t - 1];
        for (int k = 0; k < 79; ++k) {
            int idx = base + k;
            if (idx < N_NODES) {
                offs[idx] = prefix;
                cur[idx]  = prefix;
                prefix += cnt[idx];
            }
        }
        if (t == 255) offs[N_NODES] = sdata[255];
    }
    grid.sync();

    // ---- P4: CSC fill; also stage w2 LDS tile (once per block) ----
    for (int e = gtid; e < E_EDGES; e += nthr) {
        int r = eidx[e];
        int c = eidx[E_EDGES + e];
        int pos = atomicAdd(&cur[c], 1);
        src_s[pos]  = r;
        attr_s[pos] = attr[e];
    }
#pragma unroll
    for (int k = 0; k < 16; ++k) w2s[k][t] = w2[k * 256 + t];
    grid.sync();

    // ---- P5: h0 projection, block-per-row (proven structure) ----
    {
        float lw1[16], lb1[16];
#pragma unroll
        for (int k = 0; k < 16; ++k) { lw1[k] = w1[k]; lb1[k] = b1[k]; }
        float b2t = b2[t];
        for (int i = b; i < N_NODES; i += nblk) {
            if (t == 0) cnt_s = 0;
            __syncthreads();
            const float4* rowp = (const float4*)(init_m + (size_t)i * S_COLS);
#pragma unroll
            for (int p = 0; p < 4; ++p) {
                int v4 = t + p * 256;
                float4 v = rowp[v4];
                int jb = v4 * 4;
                if (v.x != 0.f) { int idx = atomicAdd(&cnt_s, 1); list[idx] = jb;     }
                if (v.y != 0.f) { int idx = atomicAdd(&cnt_s, 1); list[idx] = jb + 1; }
                if (v.z != 0.f) { int idx = atomicAdd(&cnt_s, 1); list[idx] = jb + 2; }
                if (v.w != 0.f) { int idx = atomicAdd(&cnt_s, 1); list[idx] = jb + 3; }
            }
            __syncthreads();
            int cn = cnt_s;
            float f[16] = {};
            for (int q = t; q < cn; q += 256) {
                float jf = (float)list[q];
#pragma unroll
                for (int k = 0; k < 16; ++k)
                    f[k] += fmaxf(jf * lw1[k] + lb1[k], 0.f);
            }
#pragma unroll
            for (int k = 0; k < 16; ++k) {
#pragma unroll
                for (int off = 32; off > 0; off >>= 1)
                    f[k] += __shfl_xor(f[k], off, 64);
            }
            if (lane == 0) {
#pragma unroll
                for (int k = 0; k < 16; ++k) fred[wave][k] = f[k];
            }
            __syncthreads();
            if (t < 16) ftot[t] = fred[0][t] + fred[1][t] + fred[2][t] + fred[3][t];
            __syncthreads();
            float cf = (float)cn;
            float acc = cf * b2t;
#pragma unroll
            for (int k = 0; k < 16; ++k) acc += ftot[k] * w2s[k][t];
            hbuf[(size_t)i * D_DIM + t] = f2bf(acc / fmaxf(cf, 1.f));
        }
    }
    grid.sync();

    // ---- 3 GCN layers ----
    for (int it = 0; it < 3; ++it) {
        // P6: t = h @ W (bf16 MFMA, hi+lo planes); wave job = 16 rows x 64 cols
        for (int job = gwave; job < NJOBS; job += nwave) {
            int bm = (job >> 2) * 16;
            int bn = (job & 3) * 64;
            f32x4 acc[4];
#pragma unroll
            for (int nt = 0; nt < 4; ++nt) acc[nt] = (f32x4){0.f, 0.f, 0.f, 0.f};
            const bf16_t* arow = hbuf + (size_t)(bm + id16) * D_DIM;
#pragma unroll
            for (int k0 = 0; k0 < 256; k0 += 32) {
                short8 a = *(const short8*)(arow + k0 + quad * 8);
#pragma unroll
                for (int nt = 0; nt < 4; ++nt) {
                    const bf16_t* brow = Wt_hi + (size_t)(bn + nt * 16 + id16) * D_DIM + k0 + quad * 8;
                    const bf16_t* lrow = Wt_lo + (size_t)(bn + nt * 16 + id16) * D_DIM + k0 + quad * 8;
                    short8 bh = *(const short8*)brow;
                    short8 bl = *(const short8*)lrow;
                    acc[nt] = __builtin_amdgcn_mfma_f32_16x16x32_bf16(a, bh, acc[nt], 0, 0, 0);
                    acc[nt] = __builtin_amdgcn_mfma_f32_16x16x32_bf16(a, bl, acc[nt], 0, 0, 0);
                }
            }
            // C/D: col = bn + nt*16 + id16, row = bm + quad*4 + r
#pragma unroll
            for (int nt = 0; nt < 4; ++nt) {
#pragma unroll
                for (int r = 0; r < 4; ++r) {
                    int m = bm + quad * 4 + r;
                    if (m < N_NODES)
                        tbuf[(size_t)m * D_DIM + bn + nt * 16 + id16] = f2bf(acc[nt][r]);
                }
            }
        }
        grid.sync();

        // P7: h' = relu(gather(t)); wave-per-dest, half-wave per edge, 8-deep
        for (int wid = gwave; wid < N_NODES; wid += nwave) {
            int e0 = offs[wid], e1 = offs[wid + 1];
            float acc[8] = {};
            for (int base = e0; base < e1; base += 64) {
                int n = e1 - base; if (n > 64) n = 64;
                int   r_l = 0; float a_l = 0.f;
                if (lane < n) { r_l = src_s[base + lane]; a_l = attr_s[base + lane]; }
                int nn = (n + 15) & ~15;
                for (int q = 0; q < nn; q += 16) {
#pragma unroll
                    for (int u = 0; u < 8; ++u) {
                        int   sl = q + 2 * u + half;
                        int   r  = __shfl(r_l, sl, 64);
                        float a  = __shfl(a_l, sl, 64);
                        uint4 v  = ((const uint4*)(tbuf + (size_t)r * D_DIM))[l32];
                        acc[0] += lo_bf(v.x) * a;  acc[1] += hi_bf(v.x) * a;
                        acc[2] += lo_bf(v.y) * a;  acc[3] += hi_bf(v.y) * a;
                        acc[4] += lo_bf(v.z) * a;  acc[5] += hi_bf(v.z) * a;
                        acc[6] += lo_bf(v.w) * a;  acc[7] += hi_bf(v.w) * a;
                    }
                }
            }
#pragma unroll
            for (int i = 0; i < 8; ++i) acc[i] += __shfl_xor(acc[i], 32, 64);
            if (half == 0) {
#pragma unroll
                for (int i = 0; i < 8; ++i) acc[i] = fmaxf(acc[i], 0.f);
                if (it < 2) {
                    uint4 o;
                    o.x = pack_bf(acc[0], acc[1]);
                    o.y = pack_bf(acc[2], acc[3]);
                    o.z = pack_bf(acc[4], acc[5]);
                    o.w = pack_bf(acc[6], acc[7]);
                    ((uint4*)(hbuf + (size_t)wid * D_DIM))[l32] = o;
                } else {
                    float4 o0 = { acc[0], acc[1], acc[2], acc[3] };
                    float4 o1 = { acc[4], acc[5], acc[6], acc[7] };
                    float* dst = out + (size_t)wid * D_DIM + l32 * 8;
                    *(float4*)dst       = o0;
                    *(float4*)(dst + 4) = o1;
                }
            }
        }
        if (it < 2) grid.sync();
    }
}

// ===========================================================================
// PATH B: multi-kernel fallback (proven round-6 sequence, 815 us) — used if
// the cooperative launch is rejected.
// ===========================================================================
__global__ void h0_kernel(const float* __restrict__ init_m,
                          const float* __restrict__ w1, const float* __restrict__ b1,
                          const float* __restrict__ w2, const float* __restrict__ b2,
                          bf16_t* __restrict__ h) {
    __shared__ float w2s[16][256];
    __shared__ int   list[1024];
    __shared__ int   count;
    __shared__ float fred[4][16];
    __shared__ float ftot[16];
    int i = blockIdx.x;
    int t = threadIdx.x;
#pragma unroll
    for (int k = 0; k < 16; ++k) w2s[k][t] = w2[k * D_DIM + t];
    if (t == 0) count = 0;
    __syncthreads();
    const float4* rowp = (const float4*)(init_m + (size_t)i * S_COLS);
#pragma unroll
    for (int p = 0; p < 4; ++p) {
        int v4 = t + p * 256;
        float4 v = rowp[v4];
        int jbase = v4 * 4;
        if (v.x != 0.f) { int idx = atomicAdd(&count, 1); list[idx] = jbase;     }
        if (v.y != 0.f) { int idx = atomicAdd(&count, 1); list[idx] = jbase + 1; }
        if (v.z != 0.f) { int idx = atomicAdd(&count, 1); list[idx] = jbase + 2; }
        if (v.w != 0.f) { int idx = atomicAdd(&count, 1); list[idx] = jbase + 3; }
    }
    __syncthreads();
    int cnt = count;
    float lw1[16], lb1[16];
#pragma unroll
    for (int k = 0; k < 16; ++k) { lw1[k] = w1[k]; lb1[k] = b1[k]; }
    float f[16] = {};
    for (int q = t; q < cnt; q += 256) {
        float jf = (float)list[q];
#pragma unroll
        for (int k = 0; k < 16; ++k)
            f[k] += fmaxf(jf * lw1[k] + lb1[k], 0.f);
    }
#pragma unroll
    for (int k = 0; k < 16; ++k) {
#pragma unroll
        for (int off = 32; off > 0; off >>= 1)
            f[k] += __shfl_xor(f[k], off, 64);
    }
    int wave = t >> 6, lane = t & 63;
    if (lane == 0) {
#pragma unroll
        for (int k = 0; k < 16; ++k) fred[wave][k] = f[k];
    }
    __syncthreads();
    if (t < 16) ftot[t] = fred[0][t] + fred[1][t] + fred[2][t] + fred[3][t];
    __syncthreads();
    float cf = (float)cnt;
    float acc = cf * b2[t];
#pragma unroll
    for (int k = 0; k < 16; ++k) acc += ftot[k] * w2s[k][t];
    h[(size_t)i * D_DIM + t] = f2bf(acc / fmaxf(cf, 1.f));
}

__global__ void count_kernel(const int* __restrict__ eidx, int* __restrict__ cnt) {
    int e = blockIdx.x * 256 + threadIdx.x;
    if (e < E_EDGES) atomicAdd(&cnt[eidx[E_EDGES + e]], 1);
}

__global__ void scan_kernel(const int* __restrict__ cnt, int* __restrict__ offs,
                            int* __restrict__ cur) {
    __shared__ int sdata[1024];
    int t = threadIdx.x;
    int base = t * 20;
    int vals[20];
    int local = 0;
#pragma unroll
    for (int k = 0; k < 20; ++k) {
        int idx = base + k;
        int v = (idx < N_NODES) ? cnt[idx] : 0;
        vals[k] = local;
        local += v;
    }
    sdata[t] = local;
    __syncthreads();
    for (int off = 1; off < 1024; off <<= 1) {
        int v = (t >= off) ? sdata[t - off] : 0;
        __syncthreads();
        sdata[t] += v;
        __syncthreads();
    }
    int prefix = (t == 0) ? 0 : sdata[t - 1];
#pragma unroll
    for (int k = 0; k < 20; ++k) {
        int idx = base + k;
        if (idx < N_NODES) {
            int o = prefix + vals[k];
            offs[idx] = o;
            cur[idx]  = o;
        }
    }
    if (t == 1023) offs[N_NODES] = sdata[1023];
}

__global__ void fill_kernel(const int* __restrict__ eidx, const float* __restrict__ attr,
                            int* __restrict__ cur, int* __restrict__ src_s,
                            float* __restrict__ attr_s) {
    int e = blockIdx.x * 256 + threadIdx.x;
    if (e < E_EDGES) {
        int r = eidx[e];
        int c = eidx[E_EDGES + e];
        int pos = atomicAdd(&cur[c], 1);
        src_s[pos]  = r;
        attr_s[pos] = attr[e];
    }
}

__global__ void wsplit_kernel(const float* __restrict__ W,
                              bf16_t* __restrict__ Wt_hi, bf16_t* __restrict__ Wt_lo) {
    int k = blockIdx.x;
    int n = threadIdx.x;
    float w = W[k * D_DIM + n];
    bf16_t hi = f2bf(w);
    bf16_t lo = f2bf(w - bf2f(hi));
    Wt_hi[n * D_DIM + k] = hi;
    Wt_lo[n * D_DIM + k] = lo;
}

__global__ void gemm_mfma_kernel(const bf16_t* __restrict__ h,
                                 const bf16_t* __restrict__ Wt_hi,
                                 const bf16_t* __restrict__ Wt_lo,
                                 bf16_t* __restrict__ t) {
    int w    = threadIdx.x >> 6;
    int lane = threadIdx.x & 63;
    int quad = lane >> 4;
    int id16 = lane & 15;
    int bm   = blockIdx.x * 64 + w * 16;
    int bn   = blockIdx.y * 64;
    f32x4 acc[4];
#pragma unroll
    for (int nt = 0; nt < 4; ++nt) acc[nt] = (f32x4){0.f, 0.f, 0.f, 0.f};
    const bf16_t* arow = h + (size_t)(bm + id16) * D_DIM;
#pragma unroll
    for (int k0 = 0; k0 < 256; k0 += 32) {
        short8 a = *(const short8*)(arow + k0 + quad * 8);
#pragma unroll
        for (int nt = 0; nt < 4; ++nt) {
            const bf16_t* brow = Wt_hi + (size_t)(bn + nt * 16 + id16) * D_DIM + k0 + quad * 8;
            const bf16_t* lrow = Wt_lo + (size_t)(bn + nt * 16 + id16) * D_DIM + k0 + quad * 8;
            short8 bh = *(const short8*)brow;
            short8 bl = *(const short8*)lrow;
            acc[nt] = __builtin_amdgcn_mfma_f32_16x16x32_bf16(a, bh, acc[nt], 0, 0, 0);
            acc[nt] = __builtin_amdgcn_mfma_f32_16x16x32_bf16(a, bl, acc[nt], 0, 0, 0);
        }
    }
#pragma unroll
    for (int nt = 0; nt < 4; ++nt) {
#pragma unroll
        for (int r = 0; r < 4; ++r) {
            int m = bm + quad * 4 + r;
            if (m < N_NODES)
                t[(size_t)m * D_DIM + bn + nt * 16 + id16] = f2bf(acc[nt][r]);
        }
    }
}

__global__ void gather_relu_kernel(const bf16_t* __restrict__ t,
                                   const int* __restrict__ offs,
                                   const int* __restrict__ src_s,
                                   const float* __restrict__ attr_s,
                                   bf16_t* __restrict__ hdst, float* __restrict__ fdst) {
    int wid  = (blockIdx.x * blockDim.x + threadIdx.x) >> 6;
    int lane = threadIdx.x & 63;
    if (wid >= N_NODES) return;
    int half = lane >> 5;
    int l32  = lane & 31;
    int e0 = offs[wid], e1 = offs[wid + 1];
    float acc[8] = {};
    for (int base = e0; base < e1; base += 64) {
        int n = e1 - base; if (n > 64) n = 64;
        int   r_l = 0; float a_l = 0.f;
        if (lane < n) { r_l = src_s[base + lane]; a_l = attr_s[base + lane]; }
        int nn = (n + 15) & ~15;
        for (int q = 0; q < nn; q += 16) {
#pragma unroll
            for (int u = 0; u < 8; ++u) {
                int   sl = q + 2 * u + half;
                int   r  = __shfl(r_l, sl, 64);
                float a  = __shfl(a_l, sl, 64);
                uint4 v  = ((const uint4*)(t + (size_t)r * D_DIM))[l32];
                acc[0] += lo_bf(v.x) * a;  acc[1] += hi_bf(v.x) * a;
                acc[2] += lo_bf(v.y) * a;  acc[3] += hi_bf(v.y) * a;
                acc[4] += lo_bf(v.z) * a;  acc[5] += hi_bf(v.z) * a;
                acc[6] += lo_bf(v.w) * a;  acc[7] += hi_bf(v.w) * a;
            }
        }
    }
#pragma unroll
    for (int i = 0; i < 8; ++i) acc[i] += __shfl_xor(acc[i], 32, 64);
    if (half == 0) {
#pragma unroll
        for (int i = 0; i < 8; ++i) acc[i] = fmaxf(acc[i], 0.f);
        if (hdst) {
            uint4 o;
            o.x = pack_bf(acc[0], acc[1]);
            o.y = pack_bf(acc[2], acc[3]);
            o.z = pack_bf(acc[4], acc[5]);
            o.w = pack_bf(acc[6], acc[7]);
            ((uint4*)(hdst + (size_t)wid * D_DIM))[l32] = o;
        } else {
            float4 o0 = { acc[0], acc[1], acc[2], acc[3] };
            float4 o1 = { acc[4], acc[5], acc[6], acc[7] };
            float* dst = fdst + (size_t)wid * D_DIM + l32 * 8;
            *(float4*)dst       = o0;
            *(float4*)(dst + 4) = o1;
        }
    }
}

extern "C" void kernel_launch(void* const* d_in, const int* in_sizes, int n_in,
                              void* d_out, int out_size, void* d_ws, size_t ws_size,
                              hipStream_t stream) {
    const float* init_m = (const float*)d_in[0];
    const int*   eidx   = (const int*)  d_in[1];
    const float* attr   = (const float*)d_in[2];
    const float* w1     = (const float*)d_in[3];
    const float* b1     = (const float*)d_in[4];
    const float* w2     = (const float*)d_in[5];
    const float* b2     = (const float*)d_in[6];
    const float* Wm     = (const float*)d_in[7];
    float* out = (float*)d_out;

    // Workspace layout (bytes). hbuf/tbuf = 20032 rows x 512 B (32 rows of
    // slack for the GEMM m-overread; poison is finite bf16).
    char* ws = (char*)d_ws;
    bf16_t* hbuf   = (bf16_t*)ws;                        // 10,256,384
    bf16_t* tbuf   = (bf16_t*)(ws + 10256384);           // 10,256,384
    bf16_t* Wt_hi  = (bf16_t*)(ws + 20512768);           // 131,072
    bf16_t* Wt_lo  = (bf16_t*)(ws + 20643840);           // 131,072
    int*    cnt    = (int*)   (ws + 20774912);           // 80,000
    int*    offs   = (int*)   (ws + 20854912);           // 80,004
    int*    cur    = (int*)   (ws + 20934928);           // 80,000
    int*    src_s  = (int*)   (ws + 21014928);           // 2,560,000
    float*  attr_s = (float*) (ws + 23574928);           // 2,560,000

    // --- try PATH A: occupancy-sized cooperative launch ---
    hipError_t lerr = hipErrorUnknown;
    int perCU = 0, ncu = 0, dev = 0;
    if (hipGetDevice(&dev) == hipSuccess &&
        hipDeviceGetAttribute(&ncu, hipDeviceAttributeMultiprocessorCount, dev) == hipSuccess &&
        hipOccupancyMaxActiveBlocksPerMultiprocessor(&perCU, fused_kernel, 256, 0) == hipSuccess &&
        perCU >= 1 && ncu >= 1) {
        int nblk = perCU * ncu;
        if (nblk > 1024) nblk = 1024;
        void* args[] = {
            (void*)&init_m, (void*)&eidx, (void*)&attr,
            (void*)&w1, (void*)&b1, (void*)&w2, (void*)&b2,
            (void*)&Wm, (void*)&out,
            (void*)&hbuf, (void*)&tbuf, (void*)&Wt_hi, (void*)&Wt_lo,
            (void*)&cnt, (void*)&offs, (void*)&cur, (void*)&src_s, (void*)&attr_s
        };
        lerr = hipLaunchCooperativeKernel((const void*)fused_kernel, dim3(nblk), dim3(256),
                                          args, 0, stream);
    }
    if (lerr == hipSuccess) return;

    // --- PATH B fallback: proven multi-kernel sequence ---
    hipMemsetAsync(cnt, 0, (size_t)N_NODES * sizeof(int), stream);
    count_kernel<<<(E_EDGES + 255) / 256, 256, 0, stream>>>(eidx, cnt);
    scan_kernel<<<1, 1024, 0, stream>>>(cnt, offs, cur);
    fill_kernel<<<(E_EDGES + 255) / 256, 256, 0, stream>>>(eidx, attr, cur, src_s, attr_s);
    wsplit_kernel<<<D_DIM, D_DIM, 0, stream>>>(Wm, Wt_hi, Wt_lo);
    h0_kernel<<<N_NODES, 256, 0, stream>>>(init_m, w1, b1, w2, b2, hbuf);
    dim3 ggrid((N_NODES * 64 + 255) / 256);
    dim3 mgrid((N_NODES + 63) / 64, 4);
    for (int it = 0; it < 3; ++it) {
        gemm_mfma_kernel<<<mgrid, 256, 0, stream>>>(hbuf, Wt_hi, Wt_lo, tbuf);
        if (it == 2)
            gather_relu_kernel<<<ggrid, 256, 0, stream>>>(tbuf, offs, src_s, attr_s,
                                                          (bf16_t*)nullptr, out);
        else
            gather_relu_kernel<<<ggrid, 256, 0, stream>>>(tbuf, offs, src_s, attr_s,
                                                          hbuf, (float*)nullptr);
    }
}

// Round 11
// 1006.105 us; speedup vs baseline: 1.4759x; 1.4759x over previous
//
#include <hip/hip_runtime.h>

// ============================================================================
// ROUND 11 = DIAGNOSTIC. Identical to the proven round-6 pipeline (815 us),
// except gather_relu_kernel runs 3x per layer (idempotent). dur_us delta
// directly measures per-gather cost: dur ~= 815 + 6 * gather_us.
// ============================================================================

#define N_NODES 20000
#define S_COLS  4096
#define E_EDGES 640000
#define D_DIM   256

typedef unsigned short bf16_t;
typedef __attribute__((ext_vector_type(8))) short short8;
typedef __attribute__((ext_vector_type(4))) float f32x4;

__device__ __forceinline__ float bf2f(bf16_t u) {
    union { unsigned int i; float f; } v; v.i = ((unsigned int)u) << 16; return v.f;
}
__device__ __forceinline__ bf16_t f2bf(float x) {   // round-to-nearest-even
    union { float f; unsigned int i; } v; v.f = x;
    unsigned int r = v.i + 0x7FFF + ((v.i >> 16) & 1);
    return (bf16_t)(r >> 16);
}
__device__ __forceinline__ float lo_bf(unsigned int u) {
    union { unsigned int i; float f; } v; v.i = u << 16; return v.f;
}
__device__ __forceinline__ float hi_bf(unsigned int u) {
    union { unsigned int i; float f; } v; v.i = u & 0xFFFF0000u; return v.f;
}
__device__ __forceinline__ unsigned int pack_bf(float a, float b) {
    return (unsigned int)f2bf(a) | ((unsigned int)f2bf(b) << 16);
}

// ---------------------------------------------------------------------------
// K1: h0 projection, block-per-row (proven)
// ---------------------------------------------------------------------------
__global__ void h0_kernel(const float* __restrict__ init_m,
                          const float* __restrict__ w1, const float* __restrict__ b1,
                          const float* __restrict__ w2, const float* __restrict__ b2,
                          bf16_t* __restrict__ h) {
    __shared__ float w2s[16][256];
    __shared__ int   list[1024];
    __shared__ int   count;
    __shared__ float fred[4][16];
    __shared__ float ftot[16];
    int i = blockIdx.x;
    int t = threadIdx.x;
#pragma unroll
    for (int k = 0; k < 16; ++k) w2s[k][t] = w2[k * D_DIM + t];
    if (t == 0) count = 0;
    __syncthreads();
    const float4* rowp = (const float4*)(init_m + (size_t)i * S_COLS);
#pragma unroll
    for (int p = 0; p < 4; ++p) {
        int v4 = t + p * 256;
        float4 v = rowp[v4];
        int jbase = v4 * 4;
        if (v.x != 0.f) { int idx = atomicAdd(&count, 1); list[idx] = jbase;     }
        if (v.y != 0.f) { int idx = atomicAdd(&count, 1); list[idx] = jbase + 1; }
        if (v.z != 0.f) { int idx = atomicAdd(&count, 1); list[idx] = jbase + 2; }
        if (v.w != 0.f) { int idx = atomicAdd(&count, 1); list[idx] = jbase + 3; }
    }
    __syncthreads();
    int cnt = count;
    float lw1[16], lb1[16];
#pragma unroll
    for (int k = 0; k < 16; ++k) { lw1[k] = w1[k]; lb1[k] = b1[k]; }
    float f[16] = {};
    for (int q = t; q < cnt; q += 256) {
        float jf = (float)list[q];
#pragma unroll
        for (int k = 0; k < 16; ++k)
            f[k] += fmaxf(jf * lw1[k] + lb1[k], 0.f);
    }
#pragma unroll
    for (int k = 0; k < 16; ++k) {
#pragma unroll
        for (int off = 32; off > 0; off >>= 1)
            f[k] += __shfl_xor(f[k], off, 64);
    }
    int wave = t >> 6, lane = t & 63;
    if (lane == 0) {
#pragma unroll
        for (int k = 0; k < 16; ++k) fred[wave][k] = f[k];
    }
    __syncthreads();
    if (t < 16) ftot[t] = fred[0][t] + fred[1][t] + fred[2][t] + fred[3][t];
    __syncthreads();
    float cf = (float)cnt;
    float acc = cf * b2[t];
#pragma unroll
    for (int k = 0; k < 16; ++k) acc += ftot[k] * w2s[k][t];
    h[(size_t)i * D_DIM + t] = f2bf(acc / fmaxf(cf, 1.f));
}

// ---------------------------------------------------------------------------
// CSC build
// ---------------------------------------------------------------------------
__global__ void count_kernel(const int* __restrict__ eidx, int* __restrict__ cnt) {
    int e = blockIdx.x * 256 + threadIdx.x;
    if (e < E_EDGES) atomicAdd(&cnt[eidx[E_EDGES + e]], 1);
}

__global__ void scan_kernel(const int* __restrict__ cnt, int* __restrict__ offs,
                            int* __restrict__ cur) {
    __shared__ int sdata[1024];
    int t = threadIdx.x;
    int base = t * 20;
    int vals[20];
    int local = 0;
#pragma unroll
    for (int k = 0; k < 20; ++k) {
        int idx = base + k;
        int v = (idx < N_NODES) ? cnt[idx] : 0;
        vals[k] = local;
        local += v;
    }
    sdata[t] = local;
    __syncthreads();
    for (int off = 1; off < 1024; off <<= 1) {
        int v = (t >= off) ? sdata[t - off] : 0;
        __syncthreads();
        sdata[t] += v;
        __syncthreads();
    }
    int prefix = (t == 0) ? 0 : sdata[t - 1];
#pragma unroll
    for (int k = 0; k < 20; ++k) {
        int idx = base + k;
        if (idx < N_NODES) {
            int o = prefix + vals[k];
            offs[idx] = o;
            cur[idx]  = o;
        }
    }
    if (t == 1023) offs[N_NODES] = sdata[1023];
}

__global__ void fill_kernel(const int* __restrict__ eidx, const float* __restrict__ attr,
                            int* __restrict__ cur, int* __restrict__ src_s,
                            float* __restrict__ attr_s) {
    int e = blockIdx.x * 256 + threadIdx.x;
    if (e < E_EDGES) {
        int r = eidx[e];
        int c = eidx[E_EDGES + e];
        int pos = atomicAdd(&cur[c], 1);
        src_s[pos]  = r;
        attr_s[pos] = attr[e];
    }
}

// ---------------------------------------------------------------------------
// W preprocessing
// ---------------------------------------------------------------------------
__global__ void wsplit_kernel(const float* __restrict__ W,
                              bf16_t* __restrict__ Wt_hi, bf16_t* __restrict__ Wt_lo) {
    int k = blockIdx.x;
    int n = threadIdx.x;
    float w = W[k * D_DIM + n];
    bf16_t hi = f2bf(w);
    bf16_t lo = f2bf(w - bf2f(hi));
    Wt_hi[n * D_DIM + k] = hi;
    Wt_lo[n * D_DIM + k] = lo;
}

// ---------------------------------------------------------------------------
// K3: t = h @ W (bf16 MFMA, hi+lo planes)
// ---------------------------------------------------------------------------
__global__ void gemm_mfma_kernel(const bf16_t* __restrict__ h,
                                 const bf16_t* __restrict__ Wt_hi,
                                 const bf16_t* __restrict__ Wt_lo,
                                 bf16_t* __restrict__ t) {
    int w    = threadIdx.x >> 6;
    int lane = threadIdx.x & 63;
    int quad = lane >> 4;
    int id16 = lane & 15;
    int bm   = blockIdx.x * 64 + w * 16;
    int bn   = blockIdx.y * 64;
    f32x4 acc[4];
#pragma unroll
    for (int nt = 0; nt < 4; ++nt) acc[nt] = (f32x4){0.f, 0.f, 0.f, 0.f};
    const bf16_t* arow = h + (size_t)(bm + id16) * D_DIM;
#pragma unroll
    for (int k0 = 0; k0 < 256; k0 += 32) {
        short8 a = *(const short8*)(arow + k0 + quad * 8);
#pragma unroll
        for (int nt = 0; nt < 4; ++nt) {
            const bf16_t* brow = Wt_hi + (size_t)(bn + nt * 16 + id16) * D_DIM + k0 + quad * 8;
            const bf16_t* lrow = Wt_lo + (size_t)(bn + nt * 16 + id16) * D_DIM + k0 + quad * 8;
            short8 bh = *(const short8*)brow;
            short8 bl = *(const short8*)lrow;
            acc[nt] = __builtin_amdgcn_mfma_f32_16x16x32_bf16(a, bh, acc[nt], 0, 0, 0);
            acc[nt] = __builtin_amdgcn_mfma_f32_16x16x32_bf16(a, bl, acc[nt], 0, 0, 0);
        }
    }
#pragma unroll
    for (int nt = 0; nt < 4; ++nt) {
#pragma unroll
        for (int r = 0; r < 4; ++r) {
            int m = bm + quad * 4 + r;
            if (m < N_NODES)
                t[(size_t)m * D_DIM + bn + nt * 16 + id16] = f2bf(acc[nt][r]);
        }
    }
}

// ---------------------------------------------------------------------------
// K2: gather + relu (proven round-6 version)
// ---------------------------------------------------------------------------
__global__ void gather_relu_kernel(const bf16_t* __restrict__ t,
                                   const int* __restrict__ offs,
                                   const int* __restrict__ src_s,
                                   const float* __restrict__ attr_s,
                                   bf16_t* __restrict__ hdst, float* __restrict__ fdst) {
    int wid  = (blockIdx.x * blockDim.x + threadIdx.x) >> 6;
    int lane = threadIdx.x & 63;
    if (wid >= N_NODES) return;
    int half = lane >> 5;
    int l32  = lane & 31;
    int e0 = offs[wid], e1 = offs[wid + 1];
    float acc[8] = {};
    for (int base = e0; base < e1; base += 64) {
        int n = e1 - base; if (n > 64) n = 64;
        int   r_l = 0; float a_l = 0.f;
        if (lane < n) { r_l = src_s[base + lane]; a_l = attr_s[base + lane]; }
        int nn = (n + 15) & ~15;
        for (int q = 0; q < nn; q += 16) {
#pragma unroll
            for (int u = 0; u < 8; ++u) {
                int   sl = q + 2 * u + half;
                int   r  = __shfl(r_l, sl, 64);
                float a  = __shfl(a_l, sl, 64);
                uint4 v  = ((const uint4*)(t + (size_t)r * D_DIM))[l32];
                acc[0] += lo_bf(v.x) * a;  acc[1] += hi_bf(v.x) * a;
                acc[2] += lo_bf(v.y) * a;  acc[3] += hi_bf(v.y) * a;
                acc[4] += lo_bf(v.z) * a;  acc[5] += hi_bf(v.z) * a;
                acc[6] += lo_bf(v.w) * a;  acc[7] += hi_bf(v.w) * a;
            }
        }
    }
#pragma unroll
    for (int i = 0; i < 8; ++i) acc[i] += __shfl_xor(acc[i], 32, 64);
    if (half == 0) {
#pragma unroll
        for (int i = 0; i < 8; ++i) acc[i] = fmaxf(acc[i], 0.f);
        if (hdst) {
            uint4 o;
            o.x = pack_bf(acc[0], acc[1]);
            o.y = pack_bf(acc[2], acc[3]);
            o.z = pack_bf(acc[4], acc[5]);
            o.w = pack_bf(acc[6], acc[7]);
            ((uint4*)(hdst + (size_t)wid * D_DIM))[l32] = o;
        } else {
            float4 o0 = { acc[0], acc[1], acc[2], acc[3] };
            float4 o1 = { acc[4], acc[5], acc[6], acc[7] };
            float* dst = fdst + (size_t)wid * D_DIM + l32 * 8;
            *(float4*)dst       = o0;
            *(float4*)(dst + 4) = o1;
        }
    }
}

extern "C" void kernel_launch(void* const* d_in, const int* in_sizes, int n_in,
                              void* d_out, int out_size, void* d_ws, size_t ws_size,
                              hipStream_t stream) {
    const float* init_m = (const float*)d_in[0];
    const int*   eidx   = (const int*)  d_in[1];
    const float* attr   = (const float*)d_in[2];
    const float* w1     = (const float*)d_in[3];
    const float* b1     = (const float*)d_in[4];
    const float* w2     = (const float*)d_in[5];
    const float* b2     = (const float*)d_in[6];
    const float* Wm     = (const float*)d_in[7];
    float* out = (float*)d_out;

    char* ws = (char*)d_ws;
    bf16_t* hbuf   = (bf16_t*)ws;                        // 10,256,384 (incl. slack)
    bf16_t* tbuf   = (bf16_t*)(ws + 10256384);           // 10,256,384
    bf16_t* Wt_hi  = (bf16_t*)(ws + 20512768);           // 131,072
    bf16_t* Wt_lo  = (bf16_t*)(ws + 20643840);           // 131,072
    int*    cnt    = (int*)   (ws + 20774912);           // 80,000
    int*    offs   = (int*)   (ws + 20854912);           // 80,004
    int*    cur    = (int*)   (ws + 20934928);           // 80,000
    int*    src_s  = (int*)   (ws + 21014928);           // 2,560,000
    float*  attr_s = (float*) (ws + 23574928);           // 2,560,000

    hipMemsetAsync(cnt, 0, (size_t)N_NODES * sizeof(int), stream);
    count_kernel<<<(E_EDGES + 255) / 256, 256, 0, stream>>>(eidx, cnt);
    scan_kernel<<<1, 1024, 0, stream>>>(cnt, offs, cur);
    fill_kernel<<<(E_EDGES + 255) / 256, 256, 0, stream>>>(eidx, attr, cur, src_s, attr_s);
    wsplit_kernel<<<D_DIM, D_DIM, 0, stream>>>(Wm, Wt_hi, Wt_lo);
    h0_kernel<<<N_NODES, 256, 0, stream>>>(init_m, w1, b1, w2, b2, hbuf);

    dim3 ggrid((N_NODES * 64 + 255) / 256);
    dim3 mgrid((N_NODES + 63) / 64, 4);
    for (int it = 0; it < 3; ++it) {
        gemm_mfma_kernel<<<mgrid, 256, 0, stream>>>(hbuf, Wt_hi, Wt_lo, tbuf);
        // DIAGNOSTIC: run the (idempotent) gather 3x. dur_us excess over the
        // round-6 baseline (815 us) = 6 * per-gather cost.
        for (int rep = 0; rep < 3; ++rep) {
            if (it == 2)
                gather_relu_kernel<<<ggrid, 256, 0, stream>>>(tbuf, offs, src_s, attr_s,
                                                              (bf16_t*)nullptr, out);
            else
                gather_relu_kernel<<<ggrid, 256, 0, stream>>>(tbuf, offs, src_s, attr_s,
                                                              hbuf, (float*)nullptr);
        }
    }
}